// Round 7
// baseline (182.070 us; speedup 1.0000x reference)
//
#include <hip/hip_runtime.h>

// Reprojection residual:
//   p7 = poses[cidx[i]]  (t=p7[0:3], qv=p7[3:6], qw=p7[6])
//   pt = points_param[pidx[i]]
//   uv = cross(qv, pt) + qw*pt ; pc = pt + 2*cross(qv, uv) + t
//   proj = K @ pc ; pix = proj.xy/proj.z ; out = pix - observes
//
// v7 = v6 (passed, 61us) with DOUBLE OCCUPANCY: BLK 512 -> 1024.
//  * v6 post-mortem: VALU 11%, HBM 22%, LDS ~10%, occupancy 35% -- no pipe
//    saturated => still latency-bound. Residency was 2 blocks/CU (LDS
//    2x56KB) x 512 thr = 16 waves/CU. Same LDS with 1024-thread blocks
//    = 32 waves/CU (8/SIMD, HW max). VGPR=32 <= 64 so launch_bounds(1024,8)
//    holds without spill.
//  * Loop body is BYTE-IDENTICAL to v6 (v1's arithmetic, proven absmax 2^22
//    three times). Numerics are an FMA-contraction lottery (v3/v4/v5): do
//    not touch the body, only launch geometry.
//  * LDS pose table (v6 win, -25%): 56KB stride-7 (odd -> all 32 banks).

typedef float f32x4 __attribute__((ext_vector_type(4)));

#define BLK 1024

__global__ __launch_bounds__(BLK, 8) void residual_kernel(
    const float* __restrict__ poses,
    const float* __restrict__ pts,
    const float* __restrict__ obs,
    const float* __restrict__ Km,
    const int*   __restrict__ cidx,
    const int*   __restrict__ pidx,
    float*       __restrict__ out,
    int n2,       // number of 2-point groups
    int nposef)   // pose floats = 7*C (14000 for C=2000)
{
    extern __shared__ float spose[];

    // Cooperative vectorized LDS fill: 14000 floats = 3500 float4 exactly.
    {
        int nv = nposef >> 2;
        const f32x4* src = (const f32x4*)poses;
        f32x4* dst = (f32x4*)spose;
        for (int i = (int)threadIdx.x; i < nv; i += BLK) dst[i] = src[i];
        for (int i = (nv << 2) + (int)threadIdx.x; i < nposef; i += BLK)
            spose[i] = poses[i];
    }
    __syncthreads();

    // K is wave-uniform (scalar broadcast)
    float k00 = Km[0], k01 = Km[1], k02 = Km[2];
    float k10 = Km[3], k11 = Km[4], k12 = Km[5];
    float k20 = Km[6], k21 = Km[7], k22 = Km[8];

    const int2*  ci2 = (const int2*)cidx;
    const int2*  pi2 = (const int2*)pidx;
    const f32x4* ob4 = (const f32x4*)obs;
    f32x4*       o4  = (f32x4*)out;

    const int stride = (int)gridDim.x * BLK;

    for (int g = (int)(blockIdx.x * BLK + threadIdx.x); g < n2; g += stride) {
        int2  ci = ci2[g];
        int2  pi = pi2[g];
        f32x4 ob = ob4[g];

        float pA[3], pB[3];
        __builtin_memcpy(pA, pts + 3u * (unsigned)pi.x, 12);
        __builtin_memcpy(pB, pts + 3u * (unsigned)pi.y, 12);

        const float* poA = spose + 7 * ci.x;
        const float* poB = spose + 7 * ci.y;

        f32x4 r;

        // ---- point A: v1 body, verbatim ----
        {
            float px = pA[0], py = pA[1], pz = pA[2];
            float tx = poA[0], ty = poA[1], tz = poA[2];
            float qx = poA[3], qy = poA[4], qz = poA[5], qw = poA[6];

            float ux = qy * pz - qz * py + qw * px;
            float uy = qz * px - qx * pz + qw * py;
            float uz = qx * py - qy * px + qw * pz;

            float cx = px + 2.0f * (qy * uz - qz * uy) + tx;
            float cy = py + 2.0f * (qz * ux - qx * uz) + ty;
            float cz = pz + 2.0f * (qx * uy - qy * ux) + tz;

            float w    = k20 * cx + k21 * cy + k22 * cz;
            float invw = 1.0f / w;
            float u    = (k00 * cx + k01 * cy + k02 * cz) * invw;
            float v    = (k10 * cx + k11 * cy + k12 * cz) * invw;

            r.x = u - ob.x;
            r.y = v - ob.y;
        }

        // ---- point B: v1 body, verbatim ----
        {
            float px = pB[0], py = pB[1], pz = pB[2];
            float tx = poB[0], ty = poB[1], tz = poB[2];
            float qx = poB[3], qy = poB[4], qz = poB[5], qw = poB[6];

            float ux = qy * pz - qz * py + qw * px;
            float uy = qz * px - qx * pz + qw * py;
            float uz = qx * py - qy * px + qw * pz;

            float cx = px + 2.0f * (qy * uz - qz * uy) + tx;
            float cy = py + 2.0f * (qz * ux - qx * uz) + ty;
            float cz = pz + 2.0f * (qx * uy - qy * ux) + tz;

            float w    = k20 * cx + k21 * cy + k22 * cz;
            float invw = 1.0f / w;
            float u    = (k00 * cx + k01 * cy + k02 * cz) * invw;
            float v    = (k10 * cx + k11 * cy + k12 * cz) * invw;

            r.z = u - ob.z;
            r.w = v - ob.w;
        }

        __builtin_nontemporal_store(r, &o4[g]);
    }
}

extern "C" void kernel_launch(void* const* d_in, const int* in_sizes, int n_in,
                              void* d_out, int out_size, void* d_ws, size_t ws_size,
                              hipStream_t stream) {
    const float* poses = (const float*)d_in[0];
    const float* pts   = (const float*)d_in[1];
    const float* obs   = (const float*)d_in[2];
    const float* Km    = (const float*)d_in[3];
    const int*   cidx  = (const int*)d_in[4];
    const int*   pidx  = (const int*)d_in[5];
    float* out = (float*)d_out;

    int P      = in_sizes[4];   // number of points
    int n2     = P / 2;         // 2-point groups
    int nposef = in_sizes[0];   // 7*C floats

    // 2 blocks/CU (56 KB LDS each, 1024 thr) x 256 CUs = 32 waves/CU.
    int grid = 512;
    int maxg = (n2 + BLK - 1) / BLK;
    if (grid > maxg) grid = maxg;
    size_t shmem = (size_t)nposef * sizeof(float);
    residual_kernel<<<grid, BLK, shmem, stream>>>(poses, pts, obs, Km, cidx, pidx,
                                                  out, n2, nposef);
}